// Round 1
// baseline (1109.823 us; speedup 1.0000x reference)
//
#include <hip/hip_runtime.h>
#include <math.h>

// BinaryTreeLSTM on MI355X, fp32 baseline.
// IN_DIM=300, MEM=256, N_LEAVES=8192, 13 tree levels.
//
// Fusion insight: lh=h[0::2], rh=h[1::2] => h_prev viewed as (B,512) is
// [lh|rh] contiguous, so lg+rg = h_view @ [Wl|Wr]^T : ONE (B,512)x(512,1280)
// GEMM per level. pad_xg is level-invariant -> folded into bias5[1280]
// (note pad chunk 2 feeds BOTH lf and rf slots).

#define IN_DIM 300
#define MEM 256

__device__ __forceinline__ float sigf(float x) { return 1.0f / (1.0f + __expf(-x)); }

// ---- WxT[k*1024 + c] = Wx[c*300 + k], k<300, c<1024 ----
__global__ __launch_bounds__(256) void k_transpose_wx(
    const float* __restrict__ Wx, float* __restrict__ WxT) {
  int idx = blockIdx.x * 256 + threadIdx.x;  // 307200 total
  if (idx >= 300 * 1024) return;
  int k = idx >> 10;
  int c = idx & 1023;
  WxT[idx] = Wx[c * 300 + k];
}

// ---- WcT[k*1280 + n] = (k<256 ? Wl[n*256+k] : Wr[n*256+k-256]) ----
__global__ __launch_bounds__(256) void k_transpose_wc(
    const float* __restrict__ Wl, const float* __restrict__ Wr,
    float* __restrict__ WcT) {
  int idx = blockIdx.x * 256 + threadIdx.x;  // 655360 total
  if (idx >= 512 * 1280) return;
  int k = idx / 1280;
  int n = idx - k * 1280;
  WcT[idx] = (k < 256) ? Wl[n * 256 + k] : Wr[n * 256 + (k - 256)];
}

// ---- bias5[g*256+j] = pad_xg[map[g]][j], map={0,1,2,2,3} ----
__global__ __launch_bounds__(256) void k_bias5(
    const float* __restrict__ emb_last, const float* __restrict__ Wx,
    const float* __restrict__ bx, float* __restrict__ bias5) {
  __shared__ float er[IN_DIM];
  int g = blockIdx.x;  // 0..4
  int j = threadIdx.x; // 0..255
  for (int k = threadIdx.x; k < IN_DIM; k += 256) er[k] = emb_last[k];
  __syncthreads();
  const int map[5] = {0, 1, 2, 2, 3};
  int wrow = map[g] * 256 + j;
  const float* w = Wx + wrow * IN_DIM;
  float s = bx[wrow];
  for (int k = 0; k < IN_DIM; k++) s += er[k] * w[k];
  bias5[g * 256 + j] = s;
}

// ---- Leaf: xg = embs@Wx.T + bx (chunks 0,1,3 only); c=sig(x1)*tanh(x0);
//      h = sig(x3)*tanh(c). 8 rows/block, 256 threads, thread=one column. ----
__global__ __launch_bounds__(256) void k_leaf(
    const float* __restrict__ embs, const float* __restrict__ WxT,
    const float* __restrict__ bx, float* __restrict__ cO, float* __restrict__ hO) {
  __shared__ float es[IN_DIM][8];  // transposed: es[k][r]
  int tid = threadIdx.x;
  int row0 = blockIdx.x * 8;
#pragma unroll
  for (int r = 0; r < 8; r++) {
    for (int k = tid; k < IN_DIM; k += 256) es[k][r] = embs[(row0 + r) * IN_DIM + k];
  }
  __syncthreads();
  float a0[8], a1[8], a3[8];
#pragma unroll
  for (int r = 0; r < 8; r++) { a0[r] = 0.f; a1[r] = 0.f; a3[r] = 0.f; }
#pragma unroll 2
  for (int k = 0; k < IN_DIM; k++) {
    const float* wp = WxT + k * 1024 + tid;
    float w0 = wp[0];
    float w1 = wp[256];
    float w3 = wp[768];
    const float4* hp = (const float4*)&es[k][0];
    float4 hx = hp[0], hy = hp[1];
    float hv[8] = {hx.x, hx.y, hx.z, hx.w, hy.x, hy.y, hy.z, hy.w};
#pragma unroll
    for (int r = 0; r < 8; r++) {
      a0[r] += w0 * hv[r];
      a1[r] += w1 * hv[r];
      a3[r] += w3 * hv[r];
    }
  }
  float b0 = bx[tid], b1 = bx[256 + tid], b3 = bx[768 + tid];
#pragma unroll
  for (int r = 0; r < 8; r++) {
    int gr = row0 + r;
    float u = tanhf(a0[r] + b0);
    float ig = sigf(a1[r] + b1);
    float c = ig * u;
    float o = sigf(a3[r] + b3);
    cO[gr * MEM + tid] = c;
    hO[gr * MEM + tid] = o * tanhf(c);
  }
}

// ---- Compose one level: G = h_view(B,512) @ WcT(512,1280) + bias5;
//      gates -> c,h(B,256). 8 rows/block; thread tid owns cols tid+g*256. ----
__global__ __launch_bounds__(256) void k_compose(
    const float* __restrict__ hprev, const float* __restrict__ cprev,
    const float* __restrict__ WcT, const float* __restrict__ bias5,
    float* __restrict__ cO, float* __restrict__ hO, int B) {
  __shared__ float hsm[512][8];  // transposed: hsm[k][r]
  int tid = threadIdx.x;
  int row0 = blockIdx.x * 8;
  for (int i = tid; i < 8 * 512; i += 256) {
    int r = i >> 9;
    int k = i & 511;
    int gr = row0 + r;
    hsm[k][r] = (gr < B) ? hprev[gr * 512 + k] : 0.0f;
  }
  __syncthreads();
  float a0[8], a1[8], a2[8], a3[8], a4[8];
#pragma unroll
  for (int r = 0; r < 8; r++) { a0[r] = 0.f; a1[r] = 0.f; a2[r] = 0.f; a3[r] = 0.f; a4[r] = 0.f; }
#pragma unroll 2
  for (int k = 0; k < 512; k++) {
    const float* wp = WcT + k * 1280 + tid;
    float w0 = wp[0];
    float w1 = wp[256];
    float w2 = wp[512];
    float w3 = wp[768];
    float w4 = wp[1024];
    const float4* hp = (const float4*)&hsm[k][0];
    float4 hx = hp[0], hy = hp[1];
    float hv[8] = {hx.x, hx.y, hx.z, hx.w, hy.x, hy.y, hy.z, hy.w};
#pragma unroll
    for (int r = 0; r < 8; r++) {
      a0[r] += w0 * hv[r];
      a1[r] += w1 * hv[r];
      a2[r] += w2 * hv[r];
      a3[r] += w3 * hv[r];
      a4[r] += w4 * hv[r];
    }
  }
  float b0 = bias5[tid], b1 = bias5[256 + tid], b2 = bias5[512 + tid];
  float b3 = bias5[768 + tid], b4 = bias5[1024 + tid];
#pragma unroll
  for (int r = 0; r < 8; r++) {
    int gr = row0 + r;
    if (gr >= B) return;
    float u = tanhf(a0[r] + b0);
    float ig = sigf(a1[r] + b1);
    float lf = sigf(a2[r] + b2);
    float rf = sigf(a3[r] + b3);
    float o = sigf(a4[r] + b4);
    float lc = cprev[(2 * gr) * MEM + tid];
    float rc = cprev[(2 * gr + 1) * MEM + tid];
    float c = ig * u + lf * lc + rf * rc;
    cO[gr * MEM + tid] = c;
    hO[gr * MEM + tid] = o * tanhf(c);
  }
}

extern "C" void kernel_launch(void* const* d_in, const int* in_sizes, int n_in,
                              void* d_out, int out_size, void* d_ws, size_t ws_size,
                              hipStream_t stream) {
  const float* embs = (const float*)d_in[0];
  const float* Wx = (const float*)d_in[1];
  const float* bx = (const float*)d_in[2];
  const float* Wl = (const float*)d_in[3];
  const float* Wr = (const float*)d_in[4];
  const float* emb_table = (const float*)d_in[5];
  float* out = (float*)d_out;

  // Workspace layout (floats): ~29 MB total
  float* ws = (float*)d_ws;
  float* cA = ws;                      // 8192*256
  float* hA = cA + 8192 * 256;         // 8192*256
  float* cB = hA + 8192 * 256;         // 4096*256
  float* hB = cB + 4096 * 256;         // 4096*256
  float* WcT = hB + 4096 * 256;        // 512*1280
  float* WxT = WcT + 512 * 1280;       // 300*1024
  float* bias5 = WxT + 300 * 1024;     // 1280

  // Precompute transposed weights + pad-gate bias vector
  k_transpose_wx<<<(300 * 1024) / 256, 256, 0, stream>>>(Wx, WxT);
  k_transpose_wc<<<(512 * 1280) / 256, 256, 0, stream>>>(Wl, Wr, WcT);
  k_bias5<<<5, 256, 0, stream>>>(emb_table + (in_sizes[5] - IN_DIM), Wx, bx, bias5);

  // Leaf level -> cA,hA (8192 rows)
  k_leaf<<<8192 / 8, 256, 0, stream>>>(embs, WxT, bx, cA, hA);

  // 13 tree levels, ping-pong buffers; last level writes d_out directly
  const float* cs = cA;
  const float* hs = hA;
  int B = 4096;
  int lvl = 0;
  while (B >= 1) {
    float *dc, *dh;
    if (B == 1) {
      dc = out;        // stack([c,h]) -> c first
      dh = out + 256;
    } else if ((lvl & 1) == 0) {
      dc = cB; dh = hB;
    } else {
      dc = cA; dh = hA;
    }
    k_compose<<<(B + 7) / 8, 256, 0, stream>>>(hs, cs, WcT, bias5, dc, dh, B);
    cs = dc;
    hs = dh;
    B >>= 1;
    lvl++;
  }
}

// Round 2
// 294.455 us; speedup vs baseline: 3.7691x; 3.7691x over previous
//
#include <hip/hip_runtime.h>
#include <math.h>

// BinaryTreeLSTM on MI355X — bf16 MFMA version.
// IN_DIM=300 (pad to 320), MEM=256, N_LEAVES=8192, 13 tree levels.
//
// Fusion: h_prev viewed as (B,512) row-major = [lh|rh] => one GEMM per level
// G(B,1280) = h_view @ [Wl|Wr]^T + bias5;  bias5 folds the level-invariant
// pad_xg (pad chunk 2 feeds BOTH lf and rf slots).
//
// MFMA 16x16x32 bf16, fp32 accum. c-state stays fp32 end-to-end; h stored
// bf16 (feeds next level's A operand). Weights pre-shuffled once into
// fragment-native layout: frag f = ((kc*16+grp)*NG+g), 512 ushorts/frag,
// element [lane*8+j] = B[k=kc*32+(lane>>4)*8+j][n=g*256+grp*16+(lane&15)].
// => b_frag load = coalesced 16B/lane global_load_dwordx4, L2-resident.

#define MEM 256

typedef __attribute__((ext_vector_type(8))) short bf16x8;
typedef __attribute__((ext_vector_type(4))) float f32x4;

__device__ __forceinline__ float sigf(float x) { return 1.0f / (1.0f + __expf(-x)); }

// fp32 -> bf16 (RNE)
__device__ __forceinline__ unsigned short f2b(float f) {
  unsigned int u = __float_as_uint(f);
  u = (u + 0x7FFFu + ((u >> 16) & 1u)) >> 16;
  return (unsigned short)u;
}

// ---- Wc fragment shuffle: 16 kchunks x 16 grps x 5 gates, 512 ushorts/frag ----
__global__ __launch_bounds__(256) void k_prep_wcf(
    const float* __restrict__ Wl, const float* __restrict__ Wr,
    unsigned short* __restrict__ Wcf) {
  int idx = blockIdx.x * 256 + threadIdx.x;  // 1280*512 = 655360
  if (idx >= 1280 * 512) return;
  int f = idx >> 9, r = idx & 511;
  int lane = r >> 3, j = r & 7;
  int gate = f % 5, t = f / 5;
  int grp = t & 15, kc = t >> 4;
  int k = kc * 32 + ((lane >> 4) << 3) + j;
  int col = (grp << 4) + (lane & 15);
  int n = gate * 256 + col;
  float v = (k < 256) ? Wl[n * 256 + k] : Wr[n * 256 + (k - 256)];
  Wcf[idx] = f2b(v);
}

// ---- Wx fragment shuffle: 10 kchunks x 16 grps x 3 gates {0,1,3}; k>=300 -> 0 ----
__global__ __launch_bounds__(256) void k_prep_wxf(
    const float* __restrict__ Wx, unsigned short* __restrict__ Wxf) {
  int idx = blockIdx.x * 256 + threadIdx.x;  // 480*512 = 245760
  if (idx >= 480 * 512) return;
  int f = idx >> 9, r = idx & 511;
  int lane = r >> 3, j = r & 7;
  int gate = f % 3, t = f / 3;
  int grp = t & 15, kc = t >> 4;
  int k = kc * 32 + ((lane >> 4) << 3) + j;
  int col = (grp << 4) + (lane & 15);
  const int gmap[3] = {0, 1, 3};
  int n = gmap[gate] * 256 + col;
  float v = (k < 300) ? Wx[n * 300 + k] : 0.0f;
  Wxf[idx] = f2b(v);
}

// ---- embs fp32(8192x300) -> bf16 padded (8192x320) ----
__global__ __launch_bounds__(256) void k_prep_embs(
    const float* __restrict__ embs, unsigned short* __restrict__ eb) {
  int idx = blockIdx.x * 256 + threadIdx.x;  // 8192*320 = 2621440
  if (idx >= 8192 * 320) return;
  int row = idx / 320;
  int k = idx - row * 320;
  eb[idx] = (k < 300) ? f2b(embs[row * 300 + k]) : (unsigned short)0;
}

// ---- bias5[g*256+j] = pad_xg[map[g]][j] + folded bx, fp32 exact ----
__global__ __launch_bounds__(256) void k_bias5(
    const float* __restrict__ emb_last, const float* __restrict__ Wx,
    const float* __restrict__ bx, float* __restrict__ bias5) {
  __shared__ float er[300];
  int g = blockIdx.x;   // 0..4
  int j = threadIdx.x;  // 0..255
  for (int k = threadIdx.x; k < 300; k += 256) er[k] = emb_last[k];
  __syncthreads();
  const int map[5] = {0, 1, 2, 2, 3};
  int wrow = map[g] * 256 + j;
  const float* w = Wx + wrow * 300;
  float s = bx[wrow];
  for (int k = 0; k < 300; k++) s += er[k] * w[k];
  bias5[g * 256 + j] = s;
}

// ---- Leaf: MFMA over K=320, gates {u,i,o}; c=sig*tanh; h=sig*tanh(c) ----
__global__ __launch_bounds__(256) void k_leaf_mfma(
    const unsigned short* __restrict__ eb, const unsigned short* __restrict__ Wxf,
    const float* __restrict__ bx, float* __restrict__ cO,
    unsigned short* __restrict__ hO) {
  int lane = threadIdx.x & 63;
  int wave = threadIdx.x >> 6;
  int grp = blockIdx.y * 4 + wave;       // 0..15 column group
  int m = lane & 15, quad = lane >> 4;
  int row_a = blockIdx.x * 16 + m;

  f32x4 acc0 = {0.f, 0.f, 0.f, 0.f}, acc1 = acc0, acc2 = acc0;
  const unsigned short* arow = eb + row_a * 320 + quad * 8;
#pragma unroll
  for (int kc = 0; kc < 10; kc++) {
    bf16x8 a = *(const bf16x8*)(arow + kc * 32);
    const unsigned short* bp = Wxf + ((kc * 16 + grp) * 3) * 512 + lane * 8;
    bf16x8 b0 = *(const bf16x8*)(bp);
    bf16x8 b1 = *(const bf16x8*)(bp + 512);
    bf16x8 b2 = *(const bf16x8*)(bp + 1024);
    acc0 = __builtin_amdgcn_mfma_f32_16x16x32_bf16(a, b0, acc0, 0, 0, 0);
    acc1 = __builtin_amdgcn_mfma_f32_16x16x32_bf16(a, b1, acc1, 0, 0, 0);
    acc2 = __builtin_amdgcn_mfma_f32_16x16x32_bf16(a, b2, acc2, 0, 0, 0);
  }
  int col = grp * 16 + m;
  float b0 = bx[col], b1 = bx[256 + col], b3 = bx[768 + col];
#pragma unroll
  for (int reg = 0; reg < 4; reg++) {
    int row = blockIdx.x * 16 + quad * 4 + reg;
    float u = tanhf(acc0[reg] + b0);
    float ig = sigf(acc1[reg] + b1);
    float o = sigf(acc2[reg] + b3);
    float c = ig * u;
    cO[row * MEM + col] = c;
    hO[row * MEM + col] = f2b(o * tanhf(c));
  }
}

// ---- Compose: MFMA over K=512, 5 gates; epilogue lane-local LSTM cell ----
__global__ __launch_bounds__(256) void k_compose_mfma(
    const unsigned short* __restrict__ hprev,  // B x 512 bf16
    const float* __restrict__ cprev,           // 2B x 256 fp32
    const unsigned short* __restrict__ Wcf, const float* __restrict__ bias5,
    float* __restrict__ cO, unsigned short* __restrict__ hO,
    float* __restrict__ hOf,  // non-null on final level: fp32 h out
    int B) {
  int lane = threadIdx.x & 63;
  int wave = threadIdx.x >> 6;
  int grp = blockIdx.y * 4 + wave;  // 0..15
  int m = lane & 15, quad = lane >> 4;
  int row_a = blockIdx.x * 16 + m;
  bool a_ok = (row_a < B);

  f32x4 acc0 = {0.f, 0.f, 0.f, 0.f}, acc1 = acc0, acc2 = acc0, acc3 = acc0, acc4 = acc0;
  const bf16x8 zz = {0, 0, 0, 0, 0, 0, 0, 0};
  const unsigned short* arow = hprev + row_a * 512 + quad * 8;
#pragma unroll
  for (int kc = 0; kc < 16; kc++) {
    bf16x8 a = a_ok ? *(const bf16x8*)(arow + kc * 32) : zz;
    const unsigned short* bp = Wcf + ((kc * 16 + grp) * 5) * 512 + lane * 8;
    bf16x8 b0 = *(const bf16x8*)(bp);
    bf16x8 b1 = *(const bf16x8*)(bp + 512);
    bf16x8 b2 = *(const bf16x8*)(bp + 1024);
    bf16x8 b3 = *(const bf16x8*)(bp + 1536);
    bf16x8 b4 = *(const bf16x8*)(bp + 2048);
    acc0 = __builtin_amdgcn_mfma_f32_16x16x32_bf16(a, b0, acc0, 0, 0, 0);
    acc1 = __builtin_amdgcn_mfma_f32_16x16x32_bf16(a, b1, acc1, 0, 0, 0);
    acc2 = __builtin_amdgcn_mfma_f32_16x16x32_bf16(a, b2, acc2, 0, 0, 0);
    acc3 = __builtin_amdgcn_mfma_f32_16x16x32_bf16(a, b3, acc3, 0, 0, 0);
    acc4 = __builtin_amdgcn_mfma_f32_16x16x32_bf16(a, b4, acc4, 0, 0, 0);
  }
  int col = grp * 16 + m;
  float b0 = bias5[col], b1 = bias5[256 + col], b2 = bias5[512 + col];
  float b3 = bias5[768 + col], b4 = bias5[1024 + col];
#pragma unroll
  for (int reg = 0; reg < 4; reg++) {
    int row = blockIdx.x * 16 + quad * 4 + reg;
    if (row >= B) continue;
    float u = tanhf(acc0[reg] + b0);
    float ig = sigf(acc1[reg] + b1);
    float lf = sigf(acc2[reg] + b2);
    float rf = sigf(acc3[reg] + b3);
    float o = sigf(acc4[reg] + b4);
    float lc = cprev[(2 * row) * MEM + col];
    float rc = cprev[(2 * row + 1) * MEM + col];
    float c = ig * u + lf * lc + rf * rc;
    float h = o * tanhf(c);
    cO[row * MEM + col] = c;
    hO[row * MEM + col] = f2b(h);
    if (hOf) hOf[row * MEM + col] = h;
  }
}

extern "C" void kernel_launch(void* const* d_in, const int* in_sizes, int n_in,
                              void* d_out, int out_size, void* d_ws, size_t ws_size,
                              hipStream_t stream) {
  const float* embs = (const float*)d_in[0];
  const float* Wx = (const float*)d_in[1];
  const float* bx = (const float*)d_in[2];
  const float* Wl = (const float*)d_in[3];
  const float* Wr = (const float*)d_in[4];
  const float* emb_table = (const float*)d_in[5];
  float* out = (float*)d_out;

  // Workspace layout (16B-aligned sections), ~24.7 MB
  float* ws = (float*)d_ws;
  float* cA = ws;                               // 8192*256 f32
  float* cB = cA + 8192 * 256;                  // 4096*256 f32
  float* bias5 = cB + 4096 * 256;               // 1280 f32
  unsigned short* hA = (unsigned short*)(bias5 + 1280);  // 8192*256 bf16
  unsigned short* hB = hA + 8192 * 256;                  // 4096*256 bf16
  unsigned short* Wcf = hB + 4096 * 256;                 // 1280*512
  unsigned short* Wxf = Wcf + 1280 * 512;                // 480*512
  unsigned short* eb = Wxf + 480 * 512;                  // 8192*320

  // One-time prep (graph-replayed every call; cheap)
  k_prep_wcf<<<(1280 * 512) / 256, 256, 0, stream>>>(Wl, Wr, Wcf);
  k_prep_wxf<<<(480 * 512) / 256, 256, 0, stream>>>(Wx, Wxf);
  k_prep_embs<<<(8192 * 320) / 256, 256, 0, stream>>>(embs, eb);
  k_bias5<<<5, 256, 0, stream>>>(emb_table + (in_sizes[5] - 300), Wx, bx, bias5);

  // Leaf level -> cA (f32), hA (bf16)
  k_leaf_mfma<<<dim3(8192 / 16, 4), 256, 0, stream>>>(eb, Wxf, bx, cA, hA);

  // 13 tree levels
  const float* cs = cA;
  const unsigned short* hs = hA;
  int B = 4096;
  int lvl = 0;
  while (B >= 1) {
    float* dc;
    unsigned short* dh;
    float* dhf = nullptr;
    if (B == 1) {
      dc = out;
      dh = hB;  // dummy bf16 sink
      dhf = out + 256;
    } else if ((lvl & 1) == 0) {
      dc = cB; dh = hB;
    } else {
      dc = cA; dh = hA;
    }
    k_compose_mfma<<<dim3((B + 15) / 16, 4), 256, 0, stream>>>(
        hs, cs, Wcf, bias5, dc, dh, dhf, B);
    cs = dc;
    hs = dh;
    B >>= 1;
    lvl++;
  }
}

// Round 3
// 292.049 us; speedup vs baseline: 3.8001x; 1.0082x over previous
//
#include <hip/hip_runtime.h>
#include <math.h>

// BinaryTreeLSTM on MI355X — bf16 MFMA, wave-per-tile mapping (R3).
// Key change vs R2: a block's 4 waves share ONE column group (grp=blockIdx.y)
// and cover 4 row tiles -> all waves load IDENTICAL b_frag addresses each kc,
// so L1 dedups weight reads (L2 weight traffic /4). Prep kernels fused.
//
// Fusion: h_prev viewed as (B,512) row-major = [lh|rh] => one GEMM per level
// G(B,1280) = h_view @ [Wl|Wr]^T + bias5; bias5 folds level-invariant pad_xg
// (pad chunk 2 feeds BOTH lf and rf slots). c fp32 end-to-end, h bf16.
// Weight fragment layout: frag f=((kc*16+grp)*NG+g), 512 ushorts;
// elem[lane*8+j] = W[k=kc*32+(lane>>4)*8+j][n=g*256+grp*16+(lane&15)].

#define MEM 256

typedef __attribute__((ext_vector_type(8))) short bf16x8;
typedef __attribute__((ext_vector_type(4))) float f32x4;

__device__ __forceinline__ float sigf(float x) { return 1.0f / (1.0f + __expf(-x)); }

__device__ __forceinline__ unsigned short f2b(float f) {
  unsigned int u = __float_as_uint(f);
  u = (u + 0x7FFFu + ((u >> 16) & 1u)) >> 16;
  return (unsigned short)u;
}

// ---- Fused one-time prep: Wcf shuffle | Wxf shuffle | embs->bf16 | bias5 ----
#define NB_WCF 2560
#define NB_WXF 960
#define NB_EB 10240
__global__ __launch_bounds__(256) void k_prep(
    const float* __restrict__ Wl, const float* __restrict__ Wr,
    const float* __restrict__ Wx, const float* __restrict__ bx,
    const float* __restrict__ embs, const float* __restrict__ emb_last,
    unsigned short* __restrict__ Wcf, unsigned short* __restrict__ Wxf,
    unsigned short* __restrict__ eb, float* __restrict__ bias5) {
  int b = blockIdx.x;
  if (b < NB_WCF) {
    int idx = b * 256 + threadIdx.x;  // 1280*512
    int f = idx >> 9, r = idx & 511;
    int lane = r >> 3, j = r & 7;
    int gate = f % 5, t = f / 5;
    int grp = t & 15, kc = t >> 4;
    int k = kc * 32 + ((lane >> 4) << 3) + j;
    int n = gate * 256 + (grp << 4) + (lane & 15);
    float v = (k < 256) ? Wl[n * 256 + k] : Wr[n * 256 + (k - 256)];
    Wcf[idx] = f2b(v);
  } else if (b < NB_WCF + NB_WXF) {
    int idx = (b - NB_WCF) * 256 + threadIdx.x;  // 480*512
    int f = idx >> 9, r = idx & 511;
    int lane = r >> 3, j = r & 7;
    int gate = f % 3, t = f / 3;
    int grp = t & 15, kc = t >> 4;
    int k = kc * 32 + ((lane >> 4) << 3) + j;
    const int gmap[3] = {0, 1, 3};
    int n = gmap[gate] * 256 + (grp << 4) + (lane & 15);
    float v = (k < 300) ? Wx[n * 300 + k] : 0.0f;
    Wxf[idx] = f2b(v);
  } else if (b < NB_WCF + NB_WXF + NB_EB) {
    int idx = (b - NB_WCF - NB_WXF) * 256 + threadIdx.x;  // 8192*320
    int row = idx / 320;
    int k = idx - row * 320;
    eb[idx] = (k < 300) ? f2b(embs[row * 300 + k]) : (unsigned short)0;
  } else {
    int g = b - (NB_WCF + NB_WXF + NB_EB);  // 0..4
    __shared__ float er[300];
    for (int k = threadIdx.x; k < 300; k += 256) er[k] = emb_last[k];
    __syncthreads();
    const int map[5] = {0, 1, 2, 2, 3};
    int wrow = map[g] * 256 + threadIdx.x;
    const float* w = Wx + wrow * 300;
    float s = bx[wrow];
    for (int k = 0; k < 300; k++) s += er[k] * w[k];
    bias5[g * 256 + threadIdx.x] = s;
  }
}

// ---- Leaf: grid(128,16); wave=row tile, grp=blockIdx.y (b_frags L1-shared) ----
__global__ __launch_bounds__(256) void k_leaf_mfma(
    const unsigned short* __restrict__ eb, const unsigned short* __restrict__ Wxf,
    const float* __restrict__ bx, float* __restrict__ cO,
    unsigned short* __restrict__ hO) {
  int lane = threadIdx.x & 63;
  int wave = threadIdx.x >> 6;
  int grp = blockIdx.y;              // 0..15 column group
  int tile = blockIdx.x * 4 + wave;  // 0..511 row tile
  int m = lane & 15, quad = lane >> 4;
  int row_a = tile * 16 + m;

  f32x4 acc0 = {0.f, 0.f, 0.f, 0.f}, acc1 = acc0, acc2 = acc0;
  const unsigned short* arow = eb + row_a * 320 + quad * 8;
#pragma unroll
  for (int kc = 0; kc < 10; kc++) {
    bf16x8 a = *(const bf16x8*)(arow + kc * 32);
    const unsigned short* bp = Wxf + ((kc * 16 + grp) * 3) * 512 + lane * 8;
    bf16x8 b0 = *(const bf16x8*)(bp);
    bf16x8 b1 = *(const bf16x8*)(bp + 512);
    bf16x8 b2 = *(const bf16x8*)(bp + 1024);
    acc0 = __builtin_amdgcn_mfma_f32_16x16x32_bf16(a, b0, acc0, 0, 0, 0);
    acc1 = __builtin_amdgcn_mfma_f32_16x16x32_bf16(a, b1, acc1, 0, 0, 0);
    acc2 = __builtin_amdgcn_mfma_f32_16x16x32_bf16(a, b2, acc2, 0, 0, 0);
  }
  int col = grp * 16 + m;
  float b0 = bx[col], b1 = bx[256 + col], b3 = bx[768 + col];
#pragma unroll
  for (int reg = 0; reg < 4; reg++) {
    int row = tile * 16 + quad * 4 + reg;
    float u = tanhf(acc0[reg] + b0);
    float ig = sigf(acc1[reg] + b1);
    float o = sigf(acc2[reg] + b3);
    float c = ig * u;
    cO[row * MEM + col] = c;
    hO[row * MEM + col] = f2b(o * tanhf(c));
  }
}

// ---- Compose: grid(ceil(tiles/4),16); wave=row tile, grp=blockIdx.y ----
__global__ __launch_bounds__(256) void k_compose_mfma(
    const unsigned short* __restrict__ hprev,  // B x 512 bf16
    const float* __restrict__ cprev,           // 2B x 256 fp32
    const unsigned short* __restrict__ Wcf, const float* __restrict__ bias5,
    float* __restrict__ cO, unsigned short* __restrict__ hO,
    float* __restrict__ hOf,  // non-null on final level: fp32 h out
    int B) {
  int lane = threadIdx.x & 63;
  int wave = threadIdx.x >> 6;
  int grp = blockIdx.y;              // 0..15
  int tile = blockIdx.x * 4 + wave;  // row tile
  if (tile * 16 >= B) return;        // idle wave (no barriers below)
  int m = lane & 15, quad = lane >> 4;
  int row_a = tile * 16 + m;
  bool a_ok = (row_a < B);

  f32x4 acc0 = {0.f, 0.f, 0.f, 0.f}, acc1 = acc0, acc2 = acc0, acc3 = acc0, acc4 = acc0;
  const bf16x8 zz = {0, 0, 0, 0, 0, 0, 0, 0};
  const unsigned short* arow = hprev + row_a * 512 + quad * 8;
#pragma unroll
  for (int kc = 0; kc < 16; kc++) {
    bf16x8 a = a_ok ? *(const bf16x8*)(arow + kc * 32) : zz;
    const unsigned short* bp = Wcf + ((kc * 16 + grp) * 5) * 512 + lane * 8;
    bf16x8 b0 = *(const bf16x8*)(bp);
    bf16x8 b1 = *(const bf16x8*)(bp + 512);
    bf16x8 b2 = *(const bf16x8*)(bp + 1024);
    bf16x8 b3 = *(const bf16x8*)(bp + 1536);
    bf16x8 b4 = *(const bf16x8*)(bp + 2048);
    acc0 = __builtin_amdgcn_mfma_f32_16x16x32_bf16(a, b0, acc0, 0, 0, 0);
    acc1 = __builtin_amdgcn_mfma_f32_16x16x32_bf16(a, b1, acc1, 0, 0, 0);
    acc2 = __builtin_amdgcn_mfma_f32_16x16x32_bf16(a, b2, acc2, 0, 0, 0);
    acc3 = __builtin_amdgcn_mfma_f32_16x16x32_bf16(a, b3, acc3, 0, 0, 0);
    acc4 = __builtin_amdgcn_mfma_f32_16x16x32_bf16(a, b4, acc4, 0, 0, 0);
  }
  int col = grp * 16 + m;
  float b0 = bias5[col], b1 = bias5[256 + col], b2 = bias5[512 + col];
  float b3 = bias5[768 + col], b4 = bias5[1024 + col];
#pragma unroll
  for (int reg = 0; reg < 4; reg++) {
    int row = tile * 16 + quad * 4 + reg;
    if (row >= B) continue;
    float u = tanhf(acc0[reg] + b0);
    float ig = sigf(acc1[reg] + b1);
    float lf = sigf(acc2[reg] + b2);
    float rf = sigf(acc3[reg] + b3);
    float o = sigf(acc4[reg] + b4);
    float lc = cprev[(2 * row) * MEM + col];
    float rc = cprev[(2 * row + 1) * MEM + col];
    float c = ig * u + lf * lc + rf * rc;
    float h = o * tanhf(c);
    cO[row * MEM + col] = c;
    hO[row * MEM + col] = f2b(h);
    if (hOf) hOf[row * MEM + col] = h;
  }
}

extern "C" void kernel_launch(void* const* d_in, const int* in_sizes, int n_in,
                              void* d_out, int out_size, void* d_ws, size_t ws_size,
                              hipStream_t stream) {
  const float* embs = (const float*)d_in[0];
  const float* Wx = (const float*)d_in[1];
  const float* bx = (const float*)d_in[2];
  const float* Wl = (const float*)d_in[3];
  const float* Wr = (const float*)d_in[4];
  const float* emb_table = (const float*)d_in[5];
  float* out = (float*)d_out;

  // Workspace layout, ~24.7 MB
  float* ws = (float*)d_ws;
  float* cA = ws;                               // 8192*256 f32
  float* cB = cA + 8192 * 256;                  // 4096*256 f32
  float* bias5 = cB + 4096 * 256;               // 1280 f32
  unsigned short* hA = (unsigned short*)(bias5 + 1280);  // 8192*256 bf16
  unsigned short* hB = hA + 8192 * 256;                  // 4096*256 bf16
  unsigned short* Wcf = hB + 4096 * 256;                 // 1280*512
  unsigned short* Wxf = Wcf + 1280 * 512;                // 480*512
  unsigned short* eb = Wxf + 480 * 512;                  // 8192*320

  // Fused one-time prep (13765 blocks)
  k_prep<<<NB_WCF + NB_WXF + NB_EB + 5, 256, 0, stream>>>(
      Wl, Wr, Wx, bx, embs, emb_table + (in_sizes[5] - 300),
      Wcf, Wxf, eb, bias5);

  // Leaf level -> cA (f32), hA (bf16)
  k_leaf_mfma<<<dim3(128, 16), 256, 0, stream>>>(eb, Wxf, bx, cA, hA);

  // 13 tree levels
  const float* cs = cA;
  const unsigned short* hs = hA;
  int B = 4096;
  int lvl = 0;
  while (B >= 1) {
    float* dc;
    unsigned short* dh;
    float* dhf = nullptr;
    if (B == 1) {
      dc = out;
      dh = hB;  // dummy bf16 sink
      dhf = out + 256;
    } else if ((lvl & 1) == 0) {
      dc = cB; dh = hB;
    } else {
      dc = cA; dh = hA;
    }
    int tiles = (B + 15) / 16;
    int gx = (tiles + 3) / 4;
    k_compose_mfma<<<dim3(gx, 16), 256, 0, stream>>>(
        hs, cs, Wcf, bias5, dc, dh, dhf, B);
    cs = dc;
    hs = dh;
    B >>= 1;
    lvl++;
  }
}